// Round 2
// baseline (118.090 us; speedup 1.0000x reference)
//
#include <hip/hip_runtime.h>
#include <hip/hip_bf16.h>

// Problem constants (fixed by the reference)
#define NB   8
#define C    128
#define H    112
#define W    112
#define HO   56
#define WO   56
#define KK   9      // 3x3 = 9 sigma channels
#define WAVES 16
#define CPW  8      // channels per wave = C / WAVES
#define WT_ELEMS (C * 81)   // wt[ci][kh][k*3+kw], BN-scale folded in

__device__ float g_wt[WT_ELEMS];
__device__ float g_shift[KK];

// ---------------------------------------------------------------------------
// Kernel 0: transpose conv weights to [ci][kh][k*3+kw], fold in BN scale.
// ---------------------------------------------------------------------------
__global__ void pasa_prep(const float* __restrict__ cw,
                          const float* __restrict__ bw,
                          const float* __restrict__ bb,
                          const float* __restrict__ bm,
                          const float* __restrict__ bv) {
    int idx = blockIdx.x * 256 + threadIdx.x;
    if (idx < WT_ELEMS) {
        int ci = idx / 81;
        int rem = idx % 81;
        int kh = rem / 27;
        int r2 = rem % 27;
        int k  = r2 / 3;
        int kw = r2 % 3;
        float scale = bw[k] / sqrtf(bv[k] + 1e-5f);
        g_wt[idx] = cw[((k * C + ci) * 3 + kh) * 3 + kw] * scale;
    } else if (idx < WT_ELEMS + KK) {
        int k = idx - WT_ELEMS;
        float scale = bw[k] / sqrtf(bv[k] + 1e-5f);
        g_shift[k] = bb[k] - bm[k] * scale;
    }
}

// ---------------------------------------------------------------------------
// Kernel 1: fused PASA downsample. One block per (n, ho) output row.
// 16 waves; lane = wo. XCD-swizzled blockIdx for L2 locality.
// __launch_bounds__(1024, 8): cap at 64 VGPR -> 2 blocks/CU (32 waves/CU).
// ---------------------------------------------------------------------------
__global__ __launch_bounds__(1024, 8)
void pasa_main(const float* __restrict__ x, float* __restrict__ out) {
    __shared__ float part[WAVES * KK * 64];   // 36 KB
    __shared__ float sig[KK * 57];            // padded row stride

    // XCD swizzle: grid = 448 = 8 XCDs * 56 rows; physical bid%8 = XCD.
    // All ho of one image on one XCD -> odd-row + Phase-B reuse in that L2.
    const int bid  = blockIdx.x;
    const int n    = bid & 7;
    const int ho   = bid >> 3;
    const int tid  = threadIdx.x;
    const int lane = tid & 63;
    const int wv   = __builtin_amdgcn_readfirstlane(tid >> 6);  // wave-uniform
    const int wo   = lane < WO ? lane : (WO - 1);               // clamp tail lanes

    // Reflection-resolved source rows (top reflect only: -1 -> 1).
    int rows[3];
    rows[0] = (ho == 0) ? 1 : (2 * ho - 1);
    rows[1] = 2 * ho;
    rows[2] = 2 * ho + 1;

    const float* xn = x + (size_t)n * C * H * W;
    const int ci0 = wv * CPW;

    // ---- Phase A: partial sigma over this wave's channels, 2-ch pipelined --
    float acc[KK];
#pragma unroll
    for (int k = 0; k < KK; ++k) acc[k] = 0.0f;

    auto ldrows = [&](int ci, float2* v) {
        const float* xc = xn + (size_t)ci * (H * W);
#pragma unroll
        for (int kh = 0; kh < 3; ++kh)
            v[kh] = *(const float2*)(xc + rows[kh] * W + 2 * wo);
    };
    auto consume = [&](const float2* v, const float* wb, float* a) {
#pragma unroll
        for (int kh = 0; kh < 3; ++kh) {
            const float t1 = v[kh].x;
            const float t2 = v[kh].y;
            const float t0 = __shfl_up(t2, 1);  // lane0 self = reflect(-1)=col1
            const float* wr = wb + kh * 27;     // wave-uniform -> s_load
#pragma unroll
            for (int k = 0; k < KK; ++k)
                a[k] = fmaf(t2, wr[3 * k + 2],
                       fmaf(t1, wr[3 * k + 1],
                       fmaf(t0, wr[3 * k + 0], a[k])));
        }
    };

    {
        float2 va[3], vb[3];
        ldrows(ci0 + 0, va);
        ldrows(ci0 + 1, vb);
        for (int i = 0; i < CPW; i += 2) {
            float2 na[3], nb[3];
            if (i + 2 < CPW) { ldrows(ci0 + i + 2, na); ldrows(ci0 + i + 3, nb); }
            consume(va, g_wt + (ci0 + i) * 81, acc);
            consume(vb, g_wt + (ci0 + i + 1) * 81, acc);
#pragma unroll
            for (int kh = 0; kh < 3; ++kh) { va[kh] = na[kh]; vb[kh] = nb[kh]; }
        }
    }

#pragma unroll
    for (int k = 0; k < KK; ++k) part[(wv * KK + k) * 64 + lane] = acc[k];
    __syncthreads();

    // ---- Cross-wave reduce + BN shift + clamp -----------------------------
    if (tid < KK * WO) {
        const int k = tid / WO;
        const int w_ = tid % WO;
        float s = 0.0f;
#pragma unroll
        for (int w2 = 0; w2 < WAVES; ++w2) s += part[(w2 * KK + k) * 64 + w_];
        s += g_shift[k];
        s = fmaxf(s, 1e-4f);
        sig[k * 57 + w_] = s;
    }
    __syncthreads();

    // ---- Normalize into registers (per-lane, lane = wo) -------------------
    float sg[KK];
    float tot = 0.0f;
#pragma unroll
    for (int k = 0; k < KK; ++k) { sg[k] = sig[k * 57 + wo]; tot += sg[k]; }
    const float inv = 1.0f / tot;
#pragma unroll
    for (int k = 0; k < KK; ++k) sg[k] *= inv;

    // ---- Phase B: apply adaptive filter, 2-ch pipelined -------------------
    float* on = out + ((size_t)n * C) * (HO * WO) + ho * WO;
    auto apply = [&](const float2* v) {
        float o = 0.0f;
#pragma unroll
        for (int kh = 0; kh < 3; ++kh) {
            const float t1 = v[kh].x;
            const float t2 = v[kh].y;
            const float t0 = __shfl_up(t2, 1);
            o = fmaf(t0, sg[kh * 3 + 0],
                fmaf(t1, sg[kh * 3 + 1],
                fmaf(t2, sg[kh * 3 + 2], o)));
        }
        return o;
    };
    {
        float2 va[3], vb[3];
        ldrows(ci0 + 0, va);
        ldrows(ci0 + 1, vb);
        for (int i = 0; i < CPW; i += 2) {
            float2 na[3], nb[3];
            if (i + 2 < CPW) { ldrows(ci0 + i + 2, na); ldrows(ci0 + i + 3, nb); }
            const float o0 = apply(va);
            const float o1 = apply(vb);
            if (lane < WO) {
                on[(size_t)(ci0 + i)     * (HO * WO) + lane] = o0;
                on[(size_t)(ci0 + i + 1) * (HO * WO) + lane] = o1;
            }
#pragma unroll
            for (int kh = 0; kh < 3; ++kh) { va[kh] = na[kh]; vb[kh] = nb[kh]; }
        }
    }
}

extern "C" void kernel_launch(void* const* d_in, const int* in_sizes, int n_in,
                              void* d_out, int out_size, void* d_ws, size_t ws_size,
                              hipStream_t stream) {
    const float* x   = (const float*)d_in[0];
    const float* cw  = (const float*)d_in[1];
    const float* bw  = (const float*)d_in[2];
    const float* bb  = (const float*)d_in[3];
    const float* bm  = (const float*)d_in[4];
    const float* bv  = (const float*)d_in[5];
    float* out = (float*)d_out;

    const int prep_elems = WT_ELEMS + KK;
    pasa_prep<<<(prep_elems + 255) / 256, 256, 0, stream>>>(cw, bw, bb, bm, bv);
    pasa_main<<<NB * HO, 1024, 0, stream>>>(x, out);
}